// Round 7
// baseline (697.874 us; speedup 1.0000x reference)
//
#include <hip/hip_runtime.h>

#define SS 512
#define LLc 128
#define NB 16          // batches per block
#define NG 32          // 512 / NB blocks
#define ROWB 272       // e_lds row pitch bytes (128 f16 = 256B + pad, 16B-aligned)

typedef __attribute__((ext_vector_type(4))) _Float16 half4;
typedef __attribute__((ext_vector_type(4))) float float4v;

static __device__ __forceinline__ unsigned short f2h(float f) {
    _Float16 h = (_Float16)f;
    unsigned short u;
    __builtin_memcpy(&u, &h, 2);
    return u;
}

// One block = 16 batches. Per step t: S^T = expT^T(128x128) @ E^T(128x16) via
// 16x16x16 f16 MFMA. A (expT^T) static in 16 half4 register frags per thread.
// E (f16) double-buffered in LDS, rebuilt each step. Stale-max M (exact algebra:
// lse is shift-invariant; M only controls fp range; -SAFE guards f16 overflow).
__global__ void __launch_bounds__(256, 1) crf_mfma_kernel(
    const float* __restrict__ input, const int* __restrict__ label,
    const int* __restrict__ length, const float* __restrict__ trans,
    float* __restrict__ out)
{
    const int G    = blockIdx.x;
    const int tid  = threadIdx.x;
    const int w    = tid >> 6;      // wave 0..3, owns j in [32w, 32w+32)
    const int lane = tid & 63;
    const int g16  = lane >> 4;     // 0..3
    const int q    = lane & 15;     // batch column 0..15
    const int jb   = w * 32;

    __shared__ __align__(16) unsigned char elds[2][NB * ROWB];
    __shared__ __align__(16) float wmaxT[2][NB][4];
    __shared__ float ls_lds[NB];

    // per-lane batch length (batch q of this group)
    int lenq = length[G * NB + q];
    lenq = lenq < 1 ? 1 : (lenq > SS ? SS : lenq);
    int maxlen = lenq;
    #pragma unroll
    for (int off = 1; off < 16; off <<= 1)
        maxlen = max(maxlen, __shfl_xor(maxlen, off, 64));   // block-uniform

    // ---------- label score (16 threads per batch) ----------
    {
        const int bl  = tid >> 4;    // 0..15
        const int s16 = tid & 15;
        int lenb = length[G * NB + bl];
        lenb = lenb < 1 ? 1 : (lenb > SS ? SS : lenb);
        const float* xb = input + (size_t)(G * NB + bl) * SS * LLc;
        const int*   lb = label + (size_t)(G * NB + bl) * SS;
        float acc = 0.f;
        for (int t = s16; t < lenb; t += 16) {
            const int la = lb[t];
            acc += xb[(size_t)t * LLc + la];
            if (t + 1 < lenb) acc += trans[la * LLc + lb[t + 1]];
        }
        #pragma unroll
        for (int off = 1; off < 16; off <<= 1) acc += __shfl_xor(acc, off, 64);
        if ((lane & 15) == 0) ls_lds[bl] = acc;
    }

    // ---------- A-frags: A[j][i] = exp(trans[i][j]), classic x16 layout ----------
    // frag (tt, kk): row j = jb + tt*16 + q ; k i = kk*16 + 4*g16 + e
    half4 afr[2][8];
    #pragma unroll
    for (int tt = 0; tt < 2; ++tt) {
        const int j = jb + tt * 16 + q;
        #pragma unroll
        for (int kk = 0; kk < 8; ++kk) {
            union { half4 v; unsigned short s[4]; } u;
            #pragma unroll
            for (int e = 0; e < 4; ++e) {
                const int i = kk * 16 + g16 * 4 + e;
                u.s[e] = f2h(__expf(trans[i * LLc + j]));
            }
            afr[tt][kk] = u.v;
        }
    }

    // ---------- alpha0 (C-layout: batch=q, j = jb + tt*16 + 4*g16 + r) ----------
    const float* xq = input + (size_t)(G * NB + q) * SS * LLc;
    const int j0 = jb + 4 * g16;
    const int j1 = jb + 16 + 4 * g16;

    float al[8];
    {
        float4v a0 = *(const float4v*)(xq + j0);
        float4v a1 = *(const float4v*)(xq + j1);
        #pragma unroll
        for (int r = 0; r < 4; ++r) { al[r] = a0[r]; al[4 + r] = a1[r]; }
    }

    const float SAFE = 3.0f;

    // exact M0, write e0
    {
        float m = al[0];
        #pragma unroll
        for (int k = 1; k < 8; ++k) m = fmaxf(m, al[k]);
        m = fmaxf(m, __shfl_xor(m, 16, 64));
        m = fmaxf(m, __shfl_xor(m, 32, 64));
        if (g16 == 0) wmaxT[0][q][w] = m;
    }
    __syncthreads();
    float M_add;
    {
        float4v mv = *(const float4v*)&wmaxT[0][q][0];
        M_add = fmaxf(fmaxf(mv[0], mv[1]), fmaxf(mv[2], mv[3])) + SAFE;
        #pragma unroll
        for (int tt = 0; tt < 2; ++tt) {
            unsigned u0 = (unsigned)f2h(__expf(al[tt*4+0] - M_add)) |
                          ((unsigned)f2h(__expf(al[tt*4+1] - M_add)) << 16);
            unsigned u1 = (unsigned)f2h(__expf(al[tt*4+2] - M_add)) |
                          ((unsigned)f2h(__expf(al[tt*4+3] - M_add)) << 16);
            const int jj = jb + tt * 16 + 4 * g16;
            *(uint2*)(&elds[0][q * ROWB + jj * 2]) = make_uint2(u0, u1);
        }
    }
    __syncthreads();

    // ---------- x prefetch ring (depth 3) ----------
    float4v xA[2], xB[2], xC[2];
    {
        const int t1 = 1 < maxlen ? 1 : maxlen - 1;
        const int t2 = 2 < maxlen ? 2 : maxlen - 1;
        const int t3 = 3 < maxlen ? 3 : maxlen - 1;
        xA[0] = *(const float4v*)(xq + (size_t)t1 * LLc + j0);
        xA[1] = *(const float4v*)(xq + (size_t)t1 * LLc + j1);
        xB[0] = *(const float4v*)(xq + (size_t)t2 * LLc + j0);
        xB[1] = *(const float4v*)(xq + (size_t)t2 * LLc + j1);
        xC[0] = *(const float4v*)(xq + (size_t)t3 * LLc + j0);
        xC[1] = *(const float4v*)(xq + (size_t)t3 * LLc + j1);
    }

    // ---------- forward recursion ----------
    for (int t = 1; t < maxlen; ++t) {
        const int cur = t & 1, prev = cur ^ 1;

        int tf = t + 3; tf = tf < maxlen ? tf : maxlen - 1;
        float4v xN0 = *(const float4v*)(xq + (size_t)tf * LLc + j0);
        float4v xN1 = *(const float4v*)(xq + (size_t)tf * LLc + j1);

        // stale max of alpha_{t-1} (partials written last iter, barrier'd)
        float4v mv = *(const float4v*)&wmaxT[prev][q][0];
        const float Mst = fmaxf(fmaxf(mv[0], mv[1]), fmaxf(mv[2], mv[3]));

        // B-frags from e_lds[prev] + MFMA (two j-tiles, K=128 in 8 chunks)
        float4v acc0 = {0.f, 0.f, 0.f, 0.f};
        float4v acc1 = {0.f, 0.f, 0.f, 0.f};
        #pragma unroll
        for (int kk = 0; kk < 8; ++kk) {
            half4 bf = *(const half4*)(&elds[prev][q * ROWB + (kk * 16 + 4 * g16) * 2]);
            acc0 = __builtin_amdgcn_mfma_f32_16x16x16f16(afr[0][kk], bf, acc0, 0, 0, 0);
            acc1 = __builtin_amdgcn_mfma_f32_16x16x16f16(afr[1][kk], bf, acc1, 0, 0, 0);
        }

        // alpha update (masked per batch: freeze at t >= len)
        const bool act = (t < lenq);
        #pragma unroll
        for (int r = 0; r < 4; ++r) {
            const float n0 = M_add + __logf(acc0[r]) + xA[0][r];
            const float n1 = M_add + __logf(acc1[r]) + xA[1][r];
            al[r]     = act ? n0 : al[r];
            al[4 + r] = act ? n1 : al[4 + r];
        }
        xA[0] = xB[0]; xA[1] = xB[1];
        xB[0] = xC[0]; xB[1] = xC[1];
        xC[0] = xN0;   xC[1] = xN1;

        // stale-max partials for next iter (off critical path)
        float mm = al[0];
        #pragma unroll
        for (int k = 1; k < 8; ++k) mm = fmaxf(mm, al[k]);
        mm = fmaxf(mm, __shfl_xor(mm, 16, 64));
        mm = fmaxf(mm, __shfl_xor(mm, 32, 64));
        if (g16 == 0) wmaxT[cur][q][w] = mm;

        // e_t = exp(alpha_t - (Mst + SAFE)), f16, into e_lds[cur]
        const float Me = Mst + SAFE;
        #pragma unroll
        for (int tt = 0; tt < 2; ++tt) {
            unsigned u0 = (unsigned)f2h(__expf(al[tt*4+0] - Me)) |
                          ((unsigned)f2h(__expf(al[tt*4+1] - Me)) << 16);
            unsigned u1 = (unsigned)f2h(__expf(al[tt*4+2] - Me)) |
                          ((unsigned)f2h(__expf(al[tt*4+3] - Me)) << 16);
            const int jj = jb + tt * 16 + 4 * g16;
            *(uint2*)(&elds[cur][q * ROWB + jj * 2]) = make_uint2(u0, u1);
        }
        M_add = Me;
        __syncthreads();
    }

    // ---------- final exact logsumexp per batch ----------
    {
        float mf = al[0];
        #pragma unroll
        for (int k = 1; k < 8; ++k) mf = fmaxf(mf, al[k]);
        mf = fmaxf(mf, __shfl_xor(mf, 16, 64));
        mf = fmaxf(mf, __shfl_xor(mf, 32, 64));
        if (g16 == 0) wmaxT[0][q][w] = mf;
    }
    __syncthreads();
    {
        float4v mv = *(const float4v*)&wmaxT[0][q][0];
        const float Mf = fmaxf(fmaxf(mv[0], mv[1]), fmaxf(mv[2], mv[3]));
        float s = 0.f;
        #pragma unroll
        for (int k = 0; k < 8; ++k) s += __expf(al[k] - Mf);
        s += __shfl_xor(s, 16, 64);
        s += __shfl_xor(s, 32, 64);
        if (g16 == 0) wmaxT[1][q][w] = s;
    }
    __syncthreads();
    if (tid < NB) {
        float4v mv = *(const float4v*)&wmaxT[0][tid][0];
        const float Mf = fmaxf(fmaxf(mv[0], mv[1]), fmaxf(mv[2], mv[3]));
        float4v sv = *(const float4v*)&wmaxT[1][tid][0];
        const float z = Mf + __logf(sv[0] + sv[1] + sv[2] + sv[3]);
        out[G * NB + tid] = z - ls_lds[tid];
    }
}

extern "C" void kernel_launch(void* const* d_in, const int* in_sizes, int n_in,
                              void* d_out, int out_size, void* d_ws, size_t ws_size,
                              hipStream_t stream) {
    const float* input  = (const float*)d_in[0];   // (B,S,L) f32
    const int*   label  = (const int*)d_in[1];     // (B,S) i32
    const int*   length = (const int*)d_in[2];     // (B,) i32
    const float* trans  = (const float*)d_in[3];   // (L,L) f32
    float* out = (float*)d_out;                    // (B,1) f32

    crf_mfma_kernel<<<NG, 256, 0, stream>>>(input, label, length, trans, out);
}